// Round 1
// baseline (4670.120 us; speedup 1.0000x reference)
//
#include <hip/hip_runtime.h>
#include <cstdint>
#include <cstddef>

// ---------------- constants ----------------
__constant__ int LV_N[5]    = {49152, 12288, 3072, 768, 192};   // H*W*3
__constant__ int LV_K[5]    = {2000, 2000, 2000, 768, 192};     // min(PRE_NMS, N)
__constant__ int LV_OFF[5]  = {0, 2000, 4000, 6000, 6768};      // concat offsets
__constant__ int LV_UOFF[5] = {0, 49152, 61440, 64512, 65280};  // u-array offsets
__constant__ int LV_W[5]    = {128, 64, 32, 16, 8};
__constant__ int LV_S[5]    = {4, 8, 16, 32, 64};

#define M_TOT 6960
#define U_PER_IMG 65472
#define MAX_OUT 1000

struct Ptrs { const float* cls[5]; const float* reg[5]; };

// ---------------- XLA:CPU-compatible expf (Cephes/Eigen pexp, FMA-contracted) ----
__device__ __forceinline__ float xla_expf(float x) {
  const float exp_hi = 88.3762626647950f;
  const float exp_lo = -88.3762626647949f;
  const float log2ef = 1.44269504088896341f;
  const float c1 = 0.693359375f;
  const float c2 = -2.12194440e-4f;
  const float p0 = 1.9875691500e-4f;
  const float p1 = 1.3981999507e-3f;
  const float p2 = 8.3334519073e-3f;
  const float p3 = 4.1665795894e-2f;
  const float p4 = 1.6666665459e-1f;
  const float p5 = 5.0000001201e-1f;
  float xx = fminf(fmaxf(x, exp_lo), exp_hi);
  float fx = floorf(__fmaf_rn(xx, log2ef, 0.5f));
  float r = __fmaf_rn(fx, -c1, xx);
  r = __fmaf_rn(fx, -c2, r);
  float z = __fmul_rn(r, r);
  float y = __fmaf_rn(p0, r, p1);
  y = __fmaf_rn(y, r, p2);
  y = __fmaf_rn(y, r, p3);
  y = __fmaf_rn(y, r, p4);
  y = __fmaf_rn(y, r, p5);
  y = __fmaf_rn(y, z, r);
  y = __fadd_rn(y, 1.0f);
  int n = (int)fx;
  float two_n = __uint_as_float((unsigned)(n + 127) << 23);
  return __fmul_rn(y, two_n);
}

__device__ __forceinline__ float ref_sigmoid(float x) {
  return __fdiv_rn(1.0f, __fadd_rn(1.0f, xla_expf(-x)));
}

// ================= K1: per (img,lvl) topk-select + sort + decode ==============
__global__ __launch_bounds__(1024) void k_select(Ptrs p, unsigned* u_arr,
    float* cand_box, float* cand_s, unsigned* lvl_order, unsigned* V_arr) {
  const int blk = blockIdx.x;
  const int img = blk / 5, lvl = blk % 5;
  const int N = LV_N[lvl], K = LV_K[lvl], W = LV_W[lvl], S = LV_S[lvl];
  const int HW = N / 3;
  const float* cls = p.cls[lvl] + (size_t)img * 3 * HW;
  const float* reg = p.reg[lvl] + (size_t)img * 12 * HW;
  unsigned* u = u_arr + img * U_PER_IMG + LV_UOFF[lvl];
  const int tid = threadIdx.x;

  __shared__ unsigned long long tk[2048];
  __shared__ unsigned scanA[2048];
  __shared__ unsigned scanB[2048];
  __shared__ unsigned hist[256];
  __shared__ unsigned long long sh_prefix, sh_T;
  __shared__ unsigned sh_want, sh_done, sh_cnt;

  // 1) scores (sigmoid bits; positive floats -> bits are order-isomorphic)
  for (int i = tid; i < N; i += 1024) {
    int a = i % 3, pix = i / 3;
    float logit = cls[a * HW + pix];
    u[i] = __float_as_uint(ref_sigmoid(logit));
  }
  __syncthreads();

  // 2) radix-select the K-th largest 64-bit key = (u<<32)|~idx  (unique keys)
  unsigned long long T = 0;
  if (N > K) {
    if (tid == 0) { sh_prefix = 0; sh_want = (unsigned)K; sh_done = 0; }
    __syncthreads();
    for (int d = 7; d >= 0; --d) {
      if (tid < 256) hist[tid] = 0;
      __syncthreads();
      unsigned long long prefix = sh_prefix;
      for (int i = tid; i < N; i += 1024) {
        unsigned long long key =
            ((unsigned long long)u[i] << 32) | (unsigned)(~(unsigned)i);
        bool match = (d == 7) || ((key >> (8 * (d + 1))) == prefix);
        if (match) atomicAdd(&hist[(unsigned)(key >> (8 * d)) & 255u], 1u);
      }
      __syncthreads();
      if (tid == 0) {
        unsigned want = sh_want, cum = 0; int D = 0;
        for (int v = 255; v >= 0; --v) {
          if (cum + hist[v] >= want) { D = v; break; }
          cum += hist[v];
        }
        unsigned long long np_ = (sh_prefix << 8) | (unsigned)D;
        unsigned wn = want - cum;
        if (hist[D] == wn || d == 0) { sh_T = np_ << (8 * d); sh_done = 1; }
        sh_prefix = np_; sh_want = wn;
      }
      __syncthreads();
      if (sh_done) break;
    }
    T = sh_T;
  }

  // 3) collect keys >= T into LDS
  if (tid == 0) sh_cnt = 0;
  __syncthreads();
  for (int i = tid; i < N; i += 1024) {
    unsigned long long key =
        ((unsigned long long)u[i] << 32) | (unsigned)(~(unsigned)i);
    if (key >= T) {
      unsigned slot = atomicAdd(&sh_cnt, 1u);
      if (slot < 2048u) tk[slot] = ~key;   // store bit-flipped -> sort ascending
    }
  }
  __syncthreads();
  unsigned cnt = sh_cnt;
  const int KK = K;  // LV_K already = min(PRE_NMS, N)
  for (int i2 = (int)cnt + tid; i2 < 2048; i2 += 1024) tk[i2] = ~0ULL;

  // 4) bitonic sort ascending over 2048 (CUDA-SDK pattern, dir=ascending)
  for (int size = 2; size < 2048; size <<= 1) {
    for (int stride = size >> 1; stride > 0; stride >>= 1) {
      __syncthreads();
      int pos = 2 * tid - (tid & (stride - 1));
      bool ddd = ((tid & (size >> 1)) == 0);
      unsigned long long A = tk[pos], B = tk[pos + stride];
      if ((A > B) == ddd) { tk[pos] = B; tk[pos + stride] = A; }
    }
  }
  for (int stride = 1024; stride > 0; stride >>= 1) {
    __syncthreads();
    int pos = 2 * tid - (tid & (stride - 1));
    unsigned long long A = tk[pos], B = tk[pos + stride];
    if (A > B) { tk[pos] = B; tk[pos + stride] = A; }
  }
  __syncthreads();

  // 5) decode per rank, record valid flags
  for (int r = tid; r < 2048; r += 1024) scanA[r] = 0u;
  const float MRf = 4.135166556742356f;  // |log(16/1000)| rounded to f32
  for (int r = tid; r < KK; r += 1024) {
    unsigned long long key = ~tk[r];
    unsigned ubits = (unsigned)(key >> 32);
    unsigned idx = ~((unsigned)key);
    int a = (int)(idx % 3u); int pix = (int)(idx / 3u);
    int xq = pix % W, yq = pix / W;
    float dx = reg[(a * 4 + 0) * HW + pix];
    float dy = reg[(a * 4 + 1) * HW + pix];
    float dw = reg[(a * 4 + 2) * HW + pix];
    float dh = reg[(a * 4 + 3) * HW + pix];
    // anchors in f64 exactly like numpy, rounded once to f32
    double rr = (a == 0) ? 0.5 : (a == 1 ? 1.0 : 2.0);
    double hr = sqrt(rr), wr = 1.0 / hr;
    double st = (double)S;
    double wsd = st * wr * 8.0, hsd = st * hr * 8.0;
    double sxd = (double)(xq * S), syd = (double)(yq * S);
    float a0 = (float)(sxd - 0.5 * wsd), a1 = (float)(syd - 0.5 * hsd);
    float a2 = (float)(sxd + 0.5 * wsd), a3 = (float)(syd + 0.5 * hsd);
    // decode, mirroring reference f32 ops (FMA where XLA backend contracts)
    float px = __fmul_rn(__fadd_rn(a0, a2), 0.5f);
    float py = __fmul_rn(__fadd_rn(a1, a3), 0.5f);
    float pw = __fsub_rn(a2, a0), ph = __fsub_rn(a3, a1);
    float dwc = fminf(fmaxf(dw, -MRf), MRf);
    float dhc = fminf(fmaxf(dh, -MRf), MRf);
    float gw = __fmul_rn(pw, xla_expf(dwc));
    float gh = __fmul_rn(ph, xla_expf(dhc));
    float gx = __fmaf_rn(pw, dx, px);
    float gy = __fmaf_rn(ph, dy, py);
    float x1 = fminf(fmaxf(__fmaf_rn(gw, -0.5f, gx), 0.0f), 512.0f);
    float y1 = fminf(fmaxf(__fmaf_rn(gh, -0.5f, gy), 0.0f), 512.0f);
    float x2 = fminf(fmaxf(__fmaf_rn(gw,  0.5f, gx), 0.0f), 512.0f);
    float y2 = fminf(fmaxf(__fmaf_rn(gh,  0.5f, gy), 0.0f), 512.0f);
    bool valid = (__fsub_rn(x2, x1) > 0.0f) && (__fsub_rn(y2, y1) > 0.0f);
    int pos = img * M_TOT + LV_OFF[lvl] + r;
    cand_box[(size_t)pos * 4 + 0] = x1;
    cand_box[(size_t)pos * 4 + 1] = y1;
    cand_box[(size_t)pos * 4 + 2] = x2;
    cand_box[(size_t)pos * 4 + 3] = y2;
    float score = __uint_as_float(ubits);
    cand_s[pos] = valid ? score : -1.0f;
    scanA[r] = valid ? 1u : 0u;
  }
  __syncthreads();

  // 6) stable partition (valids first) via inclusive scan over 2048
  unsigned* Ap = scanA; unsigned* Bp = scanB;
  for (int off = 1; off < 2048; off <<= 1) {
    for (int r2 = tid; r2 < 2048; r2 += 1024)
      Bp[r2] = Ap[r2] + ((r2 >= off) ? Ap[r2 - off] : 0u);
    __syncthreads();
    unsigned* t = Ap; Ap = Bp; Bp = t;
    __syncthreads();
  }
  unsigned V = (KK > 0) ? Ap[KK - 1] : 0u;
  for (int r = tid; r < KK; r += 1024) {
    unsigned incl = Ap[r];
    unsigned fl = incl - ((r > 0) ? Ap[r - 1] : 0u);
    unsigned excl = incl - fl;
    unsigned pdst = fl ? excl : V + ((unsigned)r - excl);
    lvl_order[img * M_TOT + LV_OFF[lvl] + pdst] = (unsigned)(LV_OFF[lvl] + r);
  }
  if (tid == 0) V_arr[img * 5 + lvl] = V;
}

// ================= K2: per (img,lvl) serial greedy NMS (1 wave) ===============
__global__ __launch_bounds__(64) void k_nms(const float* cand_box,
    const float* cand_s, const unsigned* lvl_order, const unsigned* V_arr,
    unsigned* kept_pos, unsigned long long* kept_key, unsigned* kept_cnt) {
  const int blk = blockIdx.x;
  const int img = blk / 5, lvl = blk % 5;
  const int K = LV_K[lvl];
  const int lane = (int)threadIdx.x;
  const float offv = (float)lvl * 513.0f;

  __shared__ float sx1[2000], sy1[2000], sx2[2000], sy2[2000];
  __shared__ float sar[2000], ssc[2000];
  __shared__ unsigned spos[2000];

  for (int j = lane; j < K; j += 64) {
    unsigned pos = lvl_order[img * M_TOT + LV_OFF[lvl] + j];
    const float* b = cand_box + (size_t)(img * M_TOT + pos) * 4;
    float x1 = __fadd_rn(b[0], offv), y1 = __fadd_rn(b[1], offv);
    float x2 = __fadd_rn(b[2], offv), y2 = __fadd_rn(b[3], offv);
    sx1[j] = x1; sy1[j] = y1; sx2[j] = x2; sy2[j] = y2;
    sar[j] = __fmul_rn(__fsub_rn(x2, x1), __fsub_rn(y2, y1));
    ssc[j] = cand_s[img * M_TOT + pos];
    spos[j] = pos;
  }
  __syncthreads();

  int V = (int)V_arr[img * 5 + lvl];
  unsigned long long alive = 0ULL;
  {
    int lo = lane * 64, hi = V < lo + 64 ? V : lo + 64;
    if (hi > lo) alive = (hi - lo == 64) ? ~0ULL : ((1ULL << (hi - lo)) - 1ULL);
  }
  int kept = 0;
  const size_t base_out = (size_t)(img * 5 + lvl) * 1024;
  for (int r = 0; r < K; ++r) {
    int w = r >> 6;
    unsigned long long aw = __shfl(alive, w);
    if (!((aw >> (r & 63)) & 1ULL)) continue;
    if (lane == 0) {
      unsigned pos = spos[r];
      kept_pos[base_out + kept] = pos;
      kept_key[base_out + kept] =
          ((unsigned long long)__float_as_uint(ssc[r]) << 32) |
          (unsigned)(~pos);
    }
    kept++;
    if (kept >= MAX_OUT) break;
    float rx1 = sx1[r], ry1 = sy1[r], rx2 = sx2[r], ry2 = sy2[r], rar = sar[r];
    for (int jb = (r + 1) & ~63; jb < K; jb += 64) {
      int j = jb + lane;
      bool sup = false;
      if (j > r && j < K) {
        float iw = fmaxf(__fsub_rn(fminf(rx2, sx2[j]), fmaxf(rx1, sx1[j])), 0.0f);
        float ih = fmaxf(__fsub_rn(fminf(ry2, sy2[j]), fmaxf(ry1, sy1[j])), 0.0f);
        float inter = __fmul_rn(iw, ih);
        float uni = __fsub_rn(__fadd_rn(rar, sar[j]), inter);
        float iou = (uni > 0.0f) ? __fdiv_rn(inter, uni) : 0.0f;
        sup = iou > 0.7f;
      }
      unsigned long long m = __ballot(sup);
      if (lane == (jb >> 6)) alive &= ~m;
    }
  }
  if (lane == 0) kept_cnt[img * 5 + lvl] = (unsigned)kept;
}

// ================= K3: per-image merge of kept lists -> output rows ===========
__global__ __launch_bounds__(256) void k_merge(const float* cand_box,
    const float* cand_s, const unsigned* kept_pos,
    const unsigned long long* kept_key, const unsigned* kept_cnt, float* out) {
  const int img = blockIdx.x;
  const int tid = (int)threadIdx.x;
  __shared__ unsigned cnts[5];
  if (tid < 5) {
    unsigned c = kept_cnt[img * 5 + tid];
    cnts[tid] = c < (unsigned)MAX_OUT ? c : (unsigned)MAX_OUT;
  }
  __syncthreads();
  unsigned T = cnts[0] + cnts[1] + cnts[2] + cnts[3] + cnts[4];
  unsigned Tc = T < (unsigned)MAX_OUT ? T : (unsigned)MAX_OUT;
  for (int r = (int)Tc + tid; r < MAX_OUT; r += 256) {
    float* o = out + (size_t)img * (MAX_OUT * 5) + (size_t)r * 5;
    o[0] = 0.f; o[1] = 0.f; o[2] = 0.f; o[3] = 0.f; o[4] = 0.f;
  }
  for (int e = tid; e < 5 * 1024; e += 256) {
    int l = e >> 10, s = e & 1023;
    if (s >= (int)cnts[l]) continue;
    unsigned long long k0 = kept_key[(size_t)(img * 5 + l) * 1024 + s];
    unsigned rank = (unsigned)s;
    for (int l2 = 0; l2 < 5; ++l2) {
      if (l2 == l) continue;
      const unsigned long long* ak = kept_key + (size_t)(img * 5 + l2) * 1024;
      int lo = 0, hi = (int)cnts[l2];
      while (lo < hi) {
        int mid = (lo + hi) >> 1;
        if (ak[mid] > k0) lo = mid + 1; else hi = mid;
      }
      rank += (unsigned)lo;
    }
    if (rank < (unsigned)MAX_OUT) {
      unsigned pos = kept_pos[(size_t)(img * 5 + l) * 1024 + s];
      const float* b = cand_box + (size_t)(img * M_TOT + pos) * 4;
      float* o = out + (size_t)img * (MAX_OUT * 5) + (size_t)rank * 5;
      o[0] = b[0]; o[1] = b[1]; o[2] = b[2]; o[3] = b[3];
      o[4] = cand_s[img * M_TOT + pos];
    }
  }
}

// ================= host launch =================
extern "C" void kernel_launch(void* const* d_in, const int* in_sizes, int n_in,
                              void* d_out, int out_size, void* d_ws, size_t ws_size,
                              hipStream_t stream) {
  Ptrs p;
  // setup_inputs order is interleaved cls0,reg0,cls1,reg1,...; detect defensively.
  bool interleaved = (n_in == 10 && in_sizes[1] == 4 * 12 * 128 * 128);
  for (int l = 0; l < 5; ++l) {
    if (interleaved) {
      p.cls[l] = (const float*)d_in[2 * l];
      p.reg[l] = (const float*)d_in[2 * l + 1];
    } else {
      p.cls[l] = (const float*)d_in[l];
      p.reg[l] = (const float*)d_in[5 + l];
    }
  }
  uint8_t* w = (uint8_t*)d_ws;
  size_t o = 0;
  auto carve = [&](size_t bytes) {
    void* ptr = w + o;
    o += (bytes + 255) & ~(size_t)255;
    return ptr;
  };
  unsigned* u_arr = (unsigned*)carve((size_t)4 * U_PER_IMG * 4);
  float* cand_box = (float*)carve((size_t)4 * M_TOT * 4 * 4);
  float* cand_s = (float*)carve((size_t)4 * M_TOT * 4);
  unsigned* lvl_order = (unsigned*)carve((size_t)4 * M_TOT * 4);
  unsigned* V_arr = (unsigned*)carve((size_t)20 * 4);
  unsigned* kept_pos = (unsigned*)carve((size_t)4 * 5 * 1024 * 4);
  unsigned long long* kept_key = (unsigned long long*)carve((size_t)4 * 5 * 1024 * 8);
  unsigned* kept_cnt = (unsigned*)carve((size_t)20 * 4);
  (void)ws_size; (void)out_size;

  k_select<<<20, 1024, 0, stream>>>(p, u_arr, cand_box, cand_s, lvl_order, V_arr);
  k_nms<<<20, 64, 0, stream>>>(cand_box, cand_s, lvl_order, V_arr,
                               kept_pos, kept_key, kept_cnt);
  k_merge<<<4, 256, 0, stream>>>(cand_box, cand_s, kept_pos, kept_key,
                                 kept_cnt, (float*)d_out);
}

// Round 2
// 441.029 us; speedup vs baseline: 10.5892x; 10.5892x over previous
//
#include <hip/hip_runtime.h>
#include <cstdint>
#include <cstddef>

// ---------------- constants ----------------
__constant__ int LV_N[5]    = {49152, 12288, 3072, 768, 192};   // H*W*3
__constant__ int LV_K[5]    = {2000, 2000, 2000, 768, 192};     // min(PRE_NMS, N)
__constant__ int LV_OFF[5]  = {0, 2000, 4000, 6000, 6768};      // concat offsets
__constant__ int LV_UOFF[5] = {0, 49152, 61440, 64512, 65280};  // u-array offsets
__constant__ int LV_W[5]    = {128, 64, 32, 16, 8};
__constant__ int LV_S[5]    = {4, 8, 16, 32, 64};
// mask geometry
__constant__ int WPL[5]     = {32, 32, 32, 12, 3};              // words per row
__constant__ int MOFF[5]    = {0, 64000, 128000, 192000, 201216}; // word offset per lvl
__constant__ int MB_BASE[6] = {0, 256, 512, 768, 804, 807};     // mask-block bases
__constant__ int MB_CT[5]   = {8, 8, 8, 3, 1};                  // col tiles per lvl

#define M_TOT 6960
#define U_PER_IMG 65472
#define MAX_OUT 1000
#define MWORDS_PER_IMG 201792

struct Ptrs { const float* cls[5]; const float* reg[5]; };

// ---------------- XLA:CPU-compatible expf (Cephes/Eigen pexp, FMA-contracted) ----
__device__ __forceinline__ float xla_expf(float x) {
  const float exp_hi = 88.3762626647950f;
  const float exp_lo = -88.3762626647949f;
  const float log2ef = 1.44269504088896341f;
  const float c1 = 0.693359375f;
  const float c2 = -2.12194440e-4f;
  const float p0 = 1.9875691500e-4f;
  const float p1 = 1.3981999507e-3f;
  const float p2 = 8.3334519073e-3f;
  const float p3 = 4.1665795894e-2f;
  const float p4 = 1.6666665459e-1f;
  const float p5 = 5.0000001201e-1f;
  float xx = fminf(fmaxf(x, exp_lo), exp_hi);
  float fx = floorf(__fmaf_rn(xx, log2ef, 0.5f));
  float r = __fmaf_rn(fx, -c1, xx);
  r = __fmaf_rn(fx, -c2, r);
  float z = __fmul_rn(r, r);
  float y = __fmaf_rn(p0, r, p1);
  y = __fmaf_rn(y, r, p2);
  y = __fmaf_rn(y, r, p3);
  y = __fmaf_rn(y, r, p4);
  y = __fmaf_rn(y, r, p5);
  y = __fmaf_rn(y, z, r);
  y = __fadd_rn(y, 1.0f);
  int n = (int)fx;
  float two_n = __uint_as_float((unsigned)(n + 127) << 23);
  return __fmul_rn(y, two_n);
}

__device__ __forceinline__ float ref_sigmoid(float x) {
  return __fdiv_rn(1.0f, __fadd_rn(1.0f, xla_expf(-x)));
}

// ================= K1: per (img,lvl) topk-select + sort + decode ==============
__global__ __launch_bounds__(1024) void k_select(Ptrs p, unsigned* u_arr,
    float* cand_box, float* cand_s,
    float* n_x1, float* n_y1, float* n_x2, float* n_y2, float* n_ar,
    float* n_sc, unsigned* n_pos, unsigned* V_arr) {
  const int blk = blockIdx.x;
  const int img = blk / 5, lvl = blk % 5;
  const int N = LV_N[lvl], K = LV_K[lvl], W = LV_W[lvl], S = LV_S[lvl];
  const int HW = N / 3;
  const float* cls = p.cls[lvl] + (size_t)img * 3 * HW;
  const float* reg = p.reg[lvl] + (size_t)img * 12 * HW;
  unsigned* u = u_arr + img * U_PER_IMG + LV_UOFF[lvl];
  const int tid = threadIdx.x;

  __shared__ unsigned long long tk[2048];
  __shared__ unsigned scanA[2048];
  __shared__ unsigned scanB[2048];
  __shared__ unsigned hist[256];
  __shared__ unsigned long long sh_prefix, sh_T;
  __shared__ unsigned sh_want, sh_done, sh_cnt;

  // 1) scores (sigmoid bits; positive floats -> bits are order-isomorphic)
  for (int i = tid; i < N; i += 1024) {
    int a = i % 3, pix = i / 3;
    float logit = cls[a * HW + pix];
    u[i] = __float_as_uint(ref_sigmoid(logit));
  }
  __syncthreads();

  // 2) radix-select the K-th largest 64-bit key = (u<<32)|~idx  (unique keys)
  unsigned long long T = 0;
  if (N > K) {
    if (tid == 0) { sh_prefix = 0; sh_want = (unsigned)K; sh_done = 0; }
    __syncthreads();
    for (int d = 7; d >= 0; --d) {
      if (tid < 256) hist[tid] = 0;
      __syncthreads();
      unsigned long long prefix = sh_prefix;
      for (int i = tid; i < N; i += 1024) {
        unsigned long long key =
            ((unsigned long long)u[i] << 32) | (unsigned)(~(unsigned)i);
        bool match = (d == 7) || ((key >> (8 * (d + 1))) == prefix);
        if (match) atomicAdd(&hist[(unsigned)(key >> (8 * d)) & 255u], 1u);
      }
      __syncthreads();
      if (tid == 0) {
        unsigned want = sh_want, cum = 0; int D = 0;
        for (int v = 255; v >= 0; --v) {
          if (cum + hist[v] >= want) { D = v; break; }
          cum += hist[v];
        }
        unsigned long long np_ = (sh_prefix << 8) | (unsigned)D;
        unsigned wn = want - cum;
        if (hist[D] == wn || d == 0) { sh_T = np_ << (8 * d); sh_done = 1; }
        sh_prefix = np_; sh_want = wn;
      }
      __syncthreads();
      if (sh_done) break;
    }
    T = sh_T;
  }

  // 3) collect keys >= T into LDS
  if (tid == 0) sh_cnt = 0;
  __syncthreads();
  for (int i = tid; i < N; i += 1024) {
    unsigned long long key =
        ((unsigned long long)u[i] << 32) | (unsigned)(~(unsigned)i);
    if (key >= T) {
      unsigned slot = atomicAdd(&sh_cnt, 1u);
      if (slot < 2048u) tk[slot] = ~key;   // store bit-flipped -> sort ascending
    }
  }
  __syncthreads();
  unsigned cnt = sh_cnt;
  const int KK = K;
  for (int i2 = (int)cnt + tid; i2 < 2048; i2 += 1024) tk[i2] = ~0ULL;

  // 4) bitonic sort ascending over 2048
  for (int size = 2; size < 2048; size <<= 1) {
    for (int stride = size >> 1; stride > 0; stride >>= 1) {
      __syncthreads();
      int pos = 2 * tid - (tid & (stride - 1));
      bool ddd = ((tid & (size >> 1)) == 0);
      unsigned long long A = tk[pos], B = tk[pos + stride];
      if ((A > B) == ddd) { tk[pos] = B; tk[pos + stride] = A; }
    }
  }
  for (int stride = 1024; stride > 0; stride >>= 1) {
    __syncthreads();
    int pos = 2 * tid - (tid & (stride - 1));
    unsigned long long A = tk[pos], B = tk[pos + stride];
    if (A > B) { tk[pos] = B; tk[pos + stride] = A; }
  }
  __syncthreads();

  // 5) decode per rank, keep boxes in registers (2 ranks/thread)
  for (int r = tid; r < 2048; r += 1024) scanA[r] = 0u;
  const float MRf = 4.135166556742356f;  // |log(16/1000)| rounded to f32
  float bx1[2], by1[2], bx2[2], by2[2], bsc[2];
  #pragma unroll
  for (int slot = 0; slot < 2; ++slot) {
    int r = tid + slot * 1024;
    if (r >= KK) continue;
    unsigned long long key = ~tk[r];
    unsigned ubits = (unsigned)(key >> 32);
    unsigned idx = ~((unsigned)key);
    int a = (int)(idx % 3u); int pix = (int)(idx / 3u);
    int xq = pix % W, yq = pix / W;
    float dx = reg[(a * 4 + 0) * HW + pix];
    float dy = reg[(a * 4 + 1) * HW + pix];
    float dw = reg[(a * 4 + 2) * HW + pix];
    float dh = reg[(a * 4 + 3) * HW + pix];
    double rr = (a == 0) ? 0.5 : (a == 1 ? 1.0 : 2.0);
    double hr = sqrt(rr), wr = 1.0 / hr;
    double st = (double)S;
    double wsd = st * wr * 8.0, hsd = st * hr * 8.0;
    double sxd = (double)(xq * S), syd = (double)(yq * S);
    float a0 = (float)(sxd - 0.5 * wsd), a1 = (float)(syd - 0.5 * hsd);
    float a2 = (float)(sxd + 0.5 * wsd), a3 = (float)(syd + 0.5 * hsd);
    float px = __fmul_rn(__fadd_rn(a0, a2), 0.5f);
    float py = __fmul_rn(__fadd_rn(a1, a3), 0.5f);
    float pw = __fsub_rn(a2, a0), ph = __fsub_rn(a3, a1);
    float dwc = fminf(fmaxf(dw, -MRf), MRf);
    float dhc = fminf(fmaxf(dh, -MRf), MRf);
    float gw = __fmul_rn(pw, xla_expf(dwc));
    float gh = __fmul_rn(ph, xla_expf(dhc));
    float gx = __fmaf_rn(pw, dx, px);
    float gy = __fmaf_rn(ph, dy, py);
    float x1 = fminf(fmaxf(__fmaf_rn(gw, -0.5f, gx), 0.0f), 512.0f);
    float y1 = fminf(fmaxf(__fmaf_rn(gh, -0.5f, gy), 0.0f), 512.0f);
    float x2 = fminf(fmaxf(__fmaf_rn(gw,  0.5f, gx), 0.0f), 512.0f);
    float y2 = fminf(fmaxf(__fmaf_rn(gh,  0.5f, gy), 0.0f), 512.0f);
    bool valid = (__fsub_rn(x2, x1) > 0.0f) && (__fsub_rn(y2, y1) > 0.0f);
    int pos = img * M_TOT + LV_OFF[lvl] + r;
    cand_box[(size_t)pos * 4 + 0] = x1;
    cand_box[(size_t)pos * 4 + 1] = y1;
    cand_box[(size_t)pos * 4 + 2] = x2;
    cand_box[(size_t)pos * 4 + 3] = y2;
    float score = __uint_as_float(ubits);
    float sc = valid ? score : -1.0f;
    cand_s[pos] = sc;
    scanA[r] = valid ? 1u : 0u;
    bx1[slot] = x1; by1[slot] = y1; bx2[slot] = x2; by2[slot] = y2;
    bsc[slot] = sc;
  }
  __syncthreads();

  // 6) stable partition (valids first) via inclusive scan over 2048
  unsigned* Ap = scanA; unsigned* Bp = scanB;
  for (int off = 1; off < 2048; off <<= 1) {
    for (int r2 = tid; r2 < 2048; r2 += 1024)
      Bp[r2] = Ap[r2] + ((r2 >= off) ? Ap[r2 - off] : 0u);
    __syncthreads();
    unsigned* t = Ap; Ap = Bp; Bp = t;
    __syncthreads();
  }
  unsigned V = (KK > 0) ? Ap[KK - 1] : 0u;
  const float offv = __fmul_rn((float)lvl, 513.0f);
  #pragma unroll
  for (int slot = 0; slot < 2; ++slot) {
    int r = tid + slot * 1024;
    if (r >= KK) continue;
    unsigned incl = Ap[r];
    unsigned fl = incl - ((r > 0) ? Ap[r - 1] : 0u);
    unsigned excl = incl - fl;
    unsigned pdst = fl ? excl : V + ((unsigned)r - excl);
    int dst = img * M_TOT + LV_OFF[lvl] + (int)pdst;
    float ox1 = __fadd_rn(bx1[slot], offv), oy1 = __fadd_rn(by1[slot], offv);
    float ox2 = __fadd_rn(bx2[slot], offv), oy2 = __fadd_rn(by2[slot], offv);
    n_x1[dst] = ox1; n_y1[dst] = oy1; n_x2[dst] = ox2; n_y2[dst] = oy2;
    n_ar[dst] = __fmul_rn(__fsub_rn(ox2, ox1), __fsub_rn(oy2, oy1));
    n_sc[dst] = bsc[slot];
    n_pos[dst] = (unsigned)(LV_OFF[lvl] + r);
  }
  if (tid == 0) V_arr[img * 5 + lvl] = V;
}

// ================= K2a: suppression bit-matrix build =========================
__global__ __launch_bounds__(256) void k_mask(
    const float* n_x1, const float* n_y1, const float* n_x2, const float* n_y2,
    const float* n_ar, unsigned long long* mask) {
  const int img = blockIdx.y;
  const int bx = blockIdx.x;
  int lvl = 0;
  while (bx >= MB_BASE[lvl + 1]) ++lvl;
  const int t = bx - MB_BASE[lvl];
  const int ct = MB_CT[lvl];
  const int rt = t / ct, c = t % ct;
  const int K = LV_K[lvl];
  const int row0 = rt * 64, col0 = c * 256;
  if (col0 + 255 <= row0) return;  // entire tile has j <= r: bits unread-harmful-never

  __shared__ float rbx[5][64];
  __shared__ float cbx[5][256];
  const int base = img * M_TOT + LV_OFF[lvl];
  const int tid = (int)threadIdx.x;
  if (tid < 64) {
    int r = row0 + tid;
    if (r < K) {
      rbx[0][tid] = n_x1[base + r]; rbx[1][tid] = n_y1[base + r];
      rbx[2][tid] = n_x2[base + r]; rbx[3][tid] = n_y2[base + r];
      rbx[4][tid] = n_ar[base + r];
    }
  }
  {
    int j = col0 + tid;
    if (j < K) {
      cbx[0][tid] = n_x1[base + j]; cbx[1][tid] = n_y1[base + j];
      cbx[2][tid] = n_x2[base + j]; cbx[3][tid] = n_y2[base + j];
      cbx[4][tid] = n_ar[base + j];
    }
  }
  __syncthreads();
  const int rl = tid >> 2, wl = tid & 3;
  const int r = row0 + rl;
  if (r >= K) return;
  const float rx1 = rbx[0][rl], ry1 = rbx[1][rl], rx2 = rbx[2][rl],
              ry2 = rbx[3][rl], rar = rbx[4][rl];
  unsigned long long word = 0ULL;
  const int jbase = wl * 64;
  #pragma unroll 8
  for (int k = 0; k < 64; ++k) {
    int kk = (k + rl) & 63;            // rotate to spread LDS banks
    int jl = jbase + kk;
    int j = col0 + jl;
    float iw = fmaxf(__fsub_rn(fminf(rx2, cbx[2][jl]), fmaxf(rx1, cbx[0][jl])), 0.0f);
    float ih = fmaxf(__fsub_rn(fminf(ry2, cbx[3][jl]), fmaxf(ry1, cbx[1][jl])), 0.0f);
    float inter = __fmul_rn(iw, ih);
    float uni = __fsub_rn(__fadd_rn(rar, cbx[4][jl]), inter);
    float iou = (uni > 0.0f) ? __fdiv_rn(inter, uni) : 0.0f;
    if (iou > 0.7f && j < K) word |= (1ULL << kk);
  }
  mask[(size_t)img * MWORDS_PER_IMG + MOFF[lvl] +
       (size_t)r * WPL[lvl] + (size_t)((col0 >> 6) + wl)] = word;
}

// ================= K2b: serial greedy scan over bit-matrix ====================
#define SCAN_D 16
__global__ __launch_bounds__(64) void k_scan(const unsigned long long* mask,
    const unsigned* n_pos, const float* n_sc, const unsigned* V_arr,
    unsigned* kept_pos, unsigned long long* kept_key, unsigned* kept_cnt) {
  const int blk = blockIdx.x;
  const int img = blk / 5, lvl = blk % 5;
  const int K = LV_K[lvl], wpl = WPL[lvl];
  const int lane = (int)threadIdx.x;
  const unsigned long long* mb =
      mask + (size_t)img * MWORDS_PER_IMG + MOFF[lvl];

  __shared__ unsigned sp[2000];
  __shared__ float ss[2000];
  const int base = img * M_TOT + LV_OFF[lvl];
  for (int j = lane; j < K; j += 64) { sp[j] = n_pos[base + j]; ss[j] = n_sc[base + j]; }

  const int V = (int)V_arr[img * 5 + lvl];
  unsigned long long alive = 0ULL;
  if (lane < wpl) {
    int lo = lane * 64, hi = V < lo + 64 ? V : lo + 64;
    if (hi > lo) alive = (hi - lo == 64) ? ~0ULL : ((1ULL << (hi - lo)) - 1ULL);
  }
  __syncthreads();

  unsigned long long rowbuf[SCAN_D], diagbuf[SCAN_D];
  #pragma unroll
  for (int d = 0; d < SCAN_D; ++d) {
    rowbuf[d] = (lane < wpl) ? mb[(size_t)d * wpl + lane] : 0ULL;
    diagbuf[d] = mb[(size_t)d * wpl + (d >> 6)];
  }

  int kept = 0;
  bool done = false;
  const size_t bo = (size_t)(img * 5 + lvl) * 1024;
  unsigned long long cw = 0ULL;
  for (int r0 = 0; r0 < K && !done; r0 += SCAN_D) {
    #pragma unroll
    for (int d = 0; d < SCAN_D; ++d) {
      int r = r0 + d;
      if ((r & 63) == 0) cw = __shfl(alive, r >> 6);
      if (!done && ((cw >> (r & 63)) & 1ULL)) {
        if (lane == 0) {
          unsigned pp = sp[r];
          kept_pos[bo + kept] = pp;
          kept_key[bo + kept] =
              ((unsigned long long)__float_as_uint(ss[r]) << 32) |
              (unsigned)(~pp);
        }
        kept++;
        if (kept >= MAX_OUT) done = true;
        cw &= ~diagbuf[d];
        alive &= ~rowbuf[d];
      }
      int nr = r + SCAN_D;
      rowbuf[d] = (lane < wpl && nr < K) ? mb[(size_t)nr * wpl + lane] : 0ULL;
      diagbuf[d] = (nr < K) ? mb[(size_t)nr * wpl + (nr >> 6)] : 0ULL;
    }
  }
  if (lane == 0) kept_cnt[img * 5 + lvl] = (unsigned)kept;
}

// ================= K3: per-image merge of kept lists -> output rows ===========
__global__ __launch_bounds__(256) void k_merge(const float* cand_box,
    const float* cand_s, const unsigned* kept_pos,
    const unsigned long long* kept_key, const unsigned* kept_cnt, float* out) {
  const int img = blockIdx.x;
  const int tid = (int)threadIdx.x;
  __shared__ unsigned cnts[5];
  if (tid < 5) {
    unsigned c = kept_cnt[img * 5 + tid];
    cnts[tid] = c < (unsigned)MAX_OUT ? c : (unsigned)MAX_OUT;
  }
  __syncthreads();
  unsigned T = cnts[0] + cnts[1] + cnts[2] + cnts[3] + cnts[4];
  unsigned Tc = T < (unsigned)MAX_OUT ? T : (unsigned)MAX_OUT;
  for (int r = (int)Tc + tid; r < MAX_OUT; r += 256) {
    float* o = out + (size_t)img * (MAX_OUT * 5) + (size_t)r * 5;
    o[0] = 0.f; o[1] = 0.f; o[2] = 0.f; o[3] = 0.f; o[4] = 0.f;
  }
  for (int e = tid; e < 5 * 1024; e += 256) {
    int l = e >> 10, s = e & 1023;
    if (s >= (int)cnts[l]) continue;
    unsigned long long k0 = kept_key[(size_t)(img * 5 + l) * 1024 + s];
    unsigned rank = (unsigned)s;
    for (int l2 = 0; l2 < 5; ++l2) {
      if (l2 == l) continue;
      const unsigned long long* ak = kept_key + (size_t)(img * 5 + l2) * 1024;
      int lo = 0, hi = (int)cnts[l2];
      while (lo < hi) {
        int mid = (lo + hi) >> 1;
        if (ak[mid] > k0) lo = mid + 1; else hi = mid;
      }
      rank += (unsigned)lo;
    }
    if (rank < (unsigned)MAX_OUT) {
      unsigned pos = kept_pos[(size_t)(img * 5 + l) * 1024 + s];
      const float* b = cand_box + (size_t)(img * M_TOT + pos) * 4;
      float* o = out + (size_t)img * (MAX_OUT * 5) + (size_t)rank * 5;
      o[0] = b[0]; o[1] = b[1]; o[2] = b[2]; o[3] = b[3];
      o[4] = cand_s[img * M_TOT + pos];
    }
  }
}

// ================= host launch =================
extern "C" void kernel_launch(void* const* d_in, const int* in_sizes, int n_in,
                              void* d_out, int out_size, void* d_ws, size_t ws_size,
                              hipStream_t stream) {
  Ptrs p;
  bool interleaved = (n_in == 10 && in_sizes[1] == 4 * 12 * 128 * 128);
  for (int l = 0; l < 5; ++l) {
    if (interleaved) {
      p.cls[l] = (const float*)d_in[2 * l];
      p.reg[l] = (const float*)d_in[2 * l + 1];
    } else {
      p.cls[l] = (const float*)d_in[l];
      p.reg[l] = (const float*)d_in[5 + l];
    }
  }
  uint8_t* w = (uint8_t*)d_ws;
  size_t o = 0;
  auto carve = [&](size_t bytes) {
    void* ptr = w + o;
    o += (bytes + 255) & ~(size_t)255;
    return ptr;
  };
  unsigned* u_arr = (unsigned*)carve((size_t)4 * U_PER_IMG * 4);
  float* cand_box = (float*)carve((size_t)4 * M_TOT * 4 * 4);
  float* cand_s = (float*)carve((size_t)4 * M_TOT * 4);
  float* n_x1 = (float*)carve((size_t)4 * M_TOT * 4);
  float* n_y1 = (float*)carve((size_t)4 * M_TOT * 4);
  float* n_x2 = (float*)carve((size_t)4 * M_TOT * 4);
  float* n_y2 = (float*)carve((size_t)4 * M_TOT * 4);
  float* n_ar = (float*)carve((size_t)4 * M_TOT * 4);
  float* n_sc = (float*)carve((size_t)4 * M_TOT * 4);
  unsigned* n_pos = (unsigned*)carve((size_t)4 * M_TOT * 4);
  unsigned* V_arr = (unsigned*)carve((size_t)20 * 4);
  unsigned* kept_pos = (unsigned*)carve((size_t)4 * 5 * 1024 * 4);
  unsigned long long* kept_key = (unsigned long long*)carve((size_t)4 * 5 * 1024 * 8);
  unsigned* kept_cnt = (unsigned*)carve((size_t)20 * 4);
  unsigned long long* mask = (unsigned long long*)carve((size_t)4 * MWORDS_PER_IMG * 8);
  (void)ws_size; (void)out_size;

  k_select<<<20, 1024, 0, stream>>>(p, u_arr, cand_box, cand_s,
      n_x1, n_y1, n_x2, n_y2, n_ar, n_sc, n_pos, V_arr);
  k_mask<<<dim3(807, 4), 256, 0, stream>>>(n_x1, n_y1, n_x2, n_y2, n_ar, mask);
  k_scan<<<20, 64, 0, stream>>>(mask, n_pos, n_sc, V_arr,
                                kept_pos, kept_key, kept_cnt);
  k_merge<<<4, 256, 0, stream>>>(cand_box, cand_s, kept_pos, kept_key,
                                 kept_cnt, (float*)d_out);
}

// Round 3
// 296.915 us; speedup vs baseline: 15.7288x; 1.4854x over previous
//
#include <hip/hip_runtime.h>
#include <cstdint>
#include <cstddef>

// ---------------- constants ----------------
__constant__ int LV_N[5]    = {49152, 12288, 3072, 768, 192};   // H*W*3
__constant__ int LV_K[5]    = {2000, 2000, 2000, 768, 192};     // min(PRE_NMS, N)
__constant__ int LV_OFF[5]  = {0, 2000, 4000, 6000, 6768};      // concat offsets
__constant__ int LV_UOFF[5] = {0, 49152, 61440, 64512, 65280};  // u-array offsets
__constant__ int LV_W[5]    = {128, 64, 32, 16, 8};
__constant__ int LV_S[5]    = {4, 8, 16, 32, 64};
// mask geometry (rows padded by 48 so the scan prefetch never needs a bounds test)
__constant__ int WPL[5]     = {32, 32, 32, 12, 3};              // words per row
__constant__ int MOFF[5]    = {0, 65536, 131072, 196608, 206400};
__constant__ int MB_BASE[6] = {0, 256, 512, 768, 804, 807};     // mask-block bases
__constant__ int MB_CT[5]   = {8, 8, 8, 3, 1};                  // col tiles per lvl

#define M_TOT 6960
#define U_PER_IMG 65472
#define MAX_OUT 1000
#define MWORDS_PER_IMG 207120
#define SCAN_D 32

struct Ptrs { const float* cls[5]; const float* reg[5]; };

// ---------------- XLA:CPU-compatible expf (Cephes/Eigen pexp, FMA-contracted) ----
__device__ __forceinline__ float xla_expf(float x) {
  const float exp_hi = 88.3762626647950f;
  const float exp_lo = -88.3762626647949f;
  const float log2ef = 1.44269504088896341f;
  const float c1 = 0.693359375f;
  const float c2 = -2.12194440e-4f;
  const float p0 = 1.9875691500e-4f;
  const float p1 = 1.3981999507e-3f;
  const float p2 = 8.3334519073e-3f;
  const float p3 = 4.1665795894e-2f;
  const float p4 = 1.6666665459e-1f;
  const float p5 = 5.0000001201e-1f;
  float xx = fminf(fmaxf(x, exp_lo), exp_hi);
  float fx = floorf(__fmaf_rn(xx, log2ef, 0.5f));
  float r = __fmaf_rn(fx, -c1, xx);
  r = __fmaf_rn(fx, -c2, r);
  float z = __fmul_rn(r, r);
  float y = __fmaf_rn(p0, r, p1);
  y = __fmaf_rn(y, r, p2);
  y = __fmaf_rn(y, r, p3);
  y = __fmaf_rn(y, r, p4);
  y = __fmaf_rn(y, r, p5);
  y = __fmaf_rn(y, z, r);
  y = __fadd_rn(y, 1.0f);
  int n = (int)fx;
  float two_n = __uint_as_float((unsigned)(n + 127) << 23);
  return __fmul_rn(y, two_n);
}

__device__ __forceinline__ float ref_sigmoid(float x) {
  return __fdiv_rn(1.0f, __fadd_rn(1.0f, xla_expf(-x)));
}

// ================= K1: per (img,lvl) topk-select + sort + decode ==============
__global__ __launch_bounds__(1024) void k_select(Ptrs p, unsigned* u_arr,
    float* cand_box, float* cand_s,
    float* n_x1, float* n_y1, float* n_x2, float* n_y2, float* n_ar,
    float* n_sc, unsigned* n_pos, unsigned* V_arr) {
  const int blk = blockIdx.x;
  const int img = blk / 5, lvl = blk % 5;
  const int N = LV_N[lvl], K = LV_K[lvl], W = LV_W[lvl], S = LV_S[lvl];
  const int HW = N / 3;
  const float* cls = p.cls[lvl] + (size_t)img * 3 * HW;
  const float* reg = p.reg[lvl] + (size_t)img * 12 * HW;
  unsigned* u = u_arr + img * U_PER_IMG + LV_UOFF[lvl];
  const int tid = threadIdx.x;

  __shared__ unsigned long long tk[2048];
  __shared__ unsigned scanA[2048];
  __shared__ unsigned scanB[2048];
  __shared__ unsigned hist[256];
  __shared__ unsigned long long sh_prefix, sh_T;
  __shared__ unsigned sh_want, sh_done, sh_cnt;

  // 1) scores (sigmoid bits; positive floats -> bits are order-isomorphic)
  for (int i = tid; i < N; i += 1024) {
    int a = i % 3, pix = i / 3;
    float logit = cls[a * HW + pix];
    u[i] = __float_as_uint(ref_sigmoid(logit));
  }
  __syncthreads();

  // 2) radix-select the K-th largest 64-bit key = (u<<32)|~idx  (unique keys)
  unsigned long long T = 0;
  if (N > K) {
    if (tid == 0) { sh_prefix = 0; sh_want = (unsigned)K; sh_done = 0; }
    __syncthreads();
    for (int d = 7; d >= 0; --d) {
      if (tid < 256) hist[tid] = 0;
      __syncthreads();
      unsigned long long prefix = sh_prefix;
      for (int i = tid; i < N; i += 1024) {
        unsigned long long key =
            ((unsigned long long)u[i] << 32) | (unsigned)(~(unsigned)i);
        bool match = (d == 7) || ((key >> (8 * (d + 1))) == prefix);
        if (match) atomicAdd(&hist[(unsigned)(key >> (8 * d)) & 255u], 1u);
      }
      __syncthreads();
      if (tid == 0) {
        unsigned want = sh_want, cum = 0; int D = 0;
        for (int v = 255; v >= 0; --v) {
          if (cum + hist[v] >= want) { D = v; break; }
          cum += hist[v];
        }
        unsigned long long np_ = (sh_prefix << 8) | (unsigned)D;
        unsigned wn = want - cum;
        if (hist[D] == wn || d == 0) { sh_T = np_ << (8 * d); sh_done = 1; }
        sh_prefix = np_; sh_want = wn;
      }
      __syncthreads();
      if (sh_done) break;
    }
    T = sh_T;
  }

  // 3) collect keys >= T into LDS
  if (tid == 0) sh_cnt = 0;
  __syncthreads();
  for (int i = tid; i < N; i += 1024) {
    unsigned long long key =
        ((unsigned long long)u[i] << 32) | (unsigned)(~(unsigned)i);
    if (key >= T) {
      unsigned slot = atomicAdd(&sh_cnt, 1u);
      if (slot < 2048u) tk[slot] = ~key;   // store bit-flipped -> sort ascending
    }
  }
  __syncthreads();
  unsigned cnt = sh_cnt;
  const int KK = K;
  for (int i2 = (int)cnt + tid; i2 < 2048; i2 += 1024) tk[i2] = ~0ULL;

  // 4) bitonic sort ascending over 2048
  for (int size = 2; size < 2048; size <<= 1) {
    for (int stride = size >> 1; stride > 0; stride >>= 1) {
      __syncthreads();
      int pos = 2 * tid - (tid & (stride - 1));
      bool ddd = ((tid & (size >> 1)) == 0);
      unsigned long long A = tk[pos], B = tk[pos + stride];
      if ((A > B) == ddd) { tk[pos] = B; tk[pos + stride] = A; }
    }
  }
  for (int stride = 1024; stride > 0; stride >>= 1) {
    __syncthreads();
    int pos = 2 * tid - (tid & (stride - 1));
    unsigned long long A = tk[pos], B = tk[pos + stride];
    if (A > B) { tk[pos] = B; tk[pos + stride] = A; }
  }
  __syncthreads();

  // 5) decode per rank, keep boxes in registers (2 ranks/thread)
  for (int r = tid; r < 2048; r += 1024) scanA[r] = 0u;
  const float MRf = 4.135166556742356f;  // |log(16/1000)| rounded to f32
  float bx1[2], by1[2], bx2[2], by2[2], bsc[2];
  #pragma unroll
  for (int slot = 0; slot < 2; ++slot) {
    int r = tid + slot * 1024;
    if (r >= KK) continue;
    unsigned long long key = ~tk[r];
    unsigned ubits = (unsigned)(key >> 32);
    unsigned idx = ~((unsigned)key);
    int a = (int)(idx % 3u); int pix = (int)(idx / 3u);
    int xq = pix % W, yq = pix / W;
    float dx = reg[(a * 4 + 0) * HW + pix];
    float dy = reg[(a * 4 + 1) * HW + pix];
    float dw = reg[(a * 4 + 2) * HW + pix];
    float dh = reg[(a * 4 + 3) * HW + pix];
    double rr = (a == 0) ? 0.5 : (a == 1 ? 1.0 : 2.0);
    double hr = sqrt(rr), wr = 1.0 / hr;
    double st = (double)S;
    double wsd = st * wr * 8.0, hsd = st * hr * 8.0;
    double sxd = (double)(xq * S), syd = (double)(yq * S);
    float a0 = (float)(sxd - 0.5 * wsd), a1 = (float)(syd - 0.5 * hsd);
    float a2 = (float)(sxd + 0.5 * wsd), a3 = (float)(syd + 0.5 * hsd);
    float px = __fmul_rn(__fadd_rn(a0, a2), 0.5f);
    float py = __fmul_rn(__fadd_rn(a1, a3), 0.5f);
    float pw = __fsub_rn(a2, a0), ph = __fsub_rn(a3, a1);
    float dwc = fminf(fmaxf(dw, -MRf), MRf);
    float dhc = fminf(fmaxf(dh, -MRf), MRf);
    float gw = __fmul_rn(pw, xla_expf(dwc));
    float gh = __fmul_rn(ph, xla_expf(dhc));
    float gx = __fmaf_rn(pw, dx, px);
    float gy = __fmaf_rn(ph, dy, py);
    float x1 = fminf(fmaxf(__fmaf_rn(gw, -0.5f, gx), 0.0f), 512.0f);
    float y1 = fminf(fmaxf(__fmaf_rn(gh, -0.5f, gy), 0.0f), 512.0f);
    float x2 = fminf(fmaxf(__fmaf_rn(gw,  0.5f, gx), 0.0f), 512.0f);
    float y2 = fminf(fmaxf(__fmaf_rn(gh,  0.5f, gy), 0.0f), 512.0f);
    bool valid = (__fsub_rn(x2, x1) > 0.0f) && (__fsub_rn(y2, y1) > 0.0f);
    int pos = img * M_TOT + LV_OFF[lvl] + r;
    cand_box[(size_t)pos * 4 + 0] = x1;
    cand_box[(size_t)pos * 4 + 1] = y1;
    cand_box[(size_t)pos * 4 + 2] = x2;
    cand_box[(size_t)pos * 4 + 3] = y2;
    float score = __uint_as_float(ubits);
    float sc = valid ? score : -1.0f;
    cand_s[pos] = sc;
    scanA[r] = valid ? 1u : 0u;
    bx1[slot] = x1; by1[slot] = y1; bx2[slot] = x2; by2[slot] = y2;
    bsc[slot] = sc;
  }
  __syncthreads();

  // 6) stable partition (valids first) via inclusive scan over 2048
  unsigned* Ap = scanA; unsigned* Bp = scanB;
  for (int off = 1; off < 2048; off <<= 1) {
    for (int r2 = tid; r2 < 2048; r2 += 1024)
      Bp[r2] = Ap[r2] + ((r2 >= off) ? Ap[r2 - off] : 0u);
    __syncthreads();
    unsigned* t = Ap; Ap = Bp; Bp = t;
    __syncthreads();
  }
  unsigned V = (KK > 0) ? Ap[KK - 1] : 0u;
  const float offv = __fmul_rn((float)lvl, 513.0f);
  #pragma unroll
  for (int slot = 0; slot < 2; ++slot) {
    int r = tid + slot * 1024;
    if (r >= KK) continue;
    unsigned incl = Ap[r];
    unsigned fl = incl - ((r > 0) ? Ap[r - 1] : 0u);
    unsigned excl = incl - fl;
    unsigned pdst = fl ? excl : V + ((unsigned)r - excl);
    int dst = img * M_TOT + LV_OFF[lvl] + (int)pdst;
    float ox1 = __fadd_rn(bx1[slot], offv), oy1 = __fadd_rn(by1[slot], offv);
    float ox2 = __fadd_rn(bx2[slot], offv), oy2 = __fadd_rn(by2[slot], offv);
    n_x1[dst] = ox1; n_y1[dst] = oy1; n_x2[dst] = ox2; n_y2[dst] = oy2;
    n_ar[dst] = __fmul_rn(__fsub_rn(ox2, ox1), __fsub_rn(oy2, oy1));
    n_sc[dst] = bsc[slot];
    n_pos[dst] = (unsigned)(LV_OFF[lvl] + r);
  }
  if (tid == 0) V_arr[img * 5 + lvl] = V;
}

// ================= K2a: suppression bit-matrix build =========================
__global__ __launch_bounds__(256) void k_mask(
    const float* n_x1, const float* n_y1, const float* n_x2, const float* n_y2,
    const float* n_ar, unsigned long long* mask) {
  const int img = blockIdx.y;
  const int bx = blockIdx.x;
  int lvl = 0;
  while (bx >= MB_BASE[lvl + 1]) ++lvl;
  const int t = bx - MB_BASE[lvl];
  const int ct = MB_CT[lvl];
  const int rt = t / ct, c = t % ct;
  const int K = LV_K[lvl];
  const int row0 = rt * 64, col0 = c * 256;
  if (col0 + 255 <= row0) return;  // entire tile has j <= r: bits never consumed

  __shared__ float rbx[5][64];
  __shared__ float cbx[5][256];
  const int base = img * M_TOT + LV_OFF[lvl];
  const int tid = (int)threadIdx.x;
  if (tid < 64) {
    int r = row0 + tid;
    if (r < K) {
      rbx[0][tid] = n_x1[base + r]; rbx[1][tid] = n_y1[base + r];
      rbx[2][tid] = n_x2[base + r]; rbx[3][tid] = n_y2[base + r];
      rbx[4][tid] = n_ar[base + r];
    }
  }
  {
    int j = col0 + tid;
    if (j < K) {
      cbx[0][tid] = n_x1[base + j]; cbx[1][tid] = n_y1[base + j];
      cbx[2][tid] = n_x2[base + j]; cbx[3][tid] = n_y2[base + j];
      cbx[4][tid] = n_ar[base + j];
    }
  }
  __syncthreads();
  const int rl = tid >> 2, wl = tid & 3;
  const int r = row0 + rl;
  if (r >= K) return;
  const float rx1 = rbx[0][rl], ry1 = rbx[1][rl], rx2 = rbx[2][rl],
              ry2 = rbx[3][rl], rar = rbx[4][rl];
  unsigned long long word = 0ULL;
  const int jbase = wl * 64;
  #pragma unroll 8
  for (int k = 0; k < 64; ++k) {
    int kk = (k + rl) & 63;            // rotate to spread LDS banks
    int jl = jbase + kk;
    int j = col0 + jl;
    float iw = fmaxf(__fsub_rn(fminf(rx2, cbx[2][jl]), fmaxf(rx1, cbx[0][jl])), 0.0f);
    float ih = fmaxf(__fsub_rn(fminf(ry2, cbx[3][jl]), fmaxf(ry1, cbx[1][jl])), 0.0f);
    float inter = __fmul_rn(iw, ih);
    float uni = __fsub_rn(__fadd_rn(rar, cbx[4][jl]), inter);
    float iou = (uni > 0.0f) ? __fdiv_rn(inter, uni) : 0.0f;
    if (iou > 0.7f && j < K) word |= (1ULL << kk);
  }
  mask[(size_t)img * MWORDS_PER_IMG + MOFF[lvl] +
       (size_t)r * WPL[lvl] + (size_t)((col0 >> 6) + wl)] = word;
}

// ================= K2b: serial greedy scan over bit-matrix ====================
// Loop body: ONE unconditional load per row + ballot keep-test. No stores, no
// conditional vmem -> compiler keeps precise vmcnt(31) waits on the 32-deep ring.
__global__ __launch_bounds__(64) void k_scan(const unsigned long long* mask,
    const unsigned* n_pos, const float* n_sc, const unsigned* V_arr,
    unsigned* kept_pos, unsigned long long* kept_key, unsigned* kept_cnt) {
  const int blk = blockIdx.x;
  const int img = blk / 5, lvl = blk % 5;
  const int K = LV_K[lvl], wpl = WPL[lvl];
  const int lane = (int)threadIdx.x;
  const unsigned long long* mb =
      mask + (size_t)img * MWORDS_PER_IMG + MOFF[lvl];
  const int ln = lane < wpl ? lane : 0;  // clamped word index (dup loads ok)

  __shared__ unsigned skept[MAX_OUT];

  const int V = (int)V_arr[img * 5 + lvl];
  unsigned long long alive = 0ULL;
  if (lane < wpl) {
    int lo = lane * 64, hi = V < lo + 64 ? V : lo + 64;
    if (hi > lo) alive = (hi - lo == 64) ? ~0ULL : ((1ULL << (hi - lo)) - 1ULL);
  }

  unsigned long long rowbuf[SCAN_D];
  #pragma unroll
  for (int d = 0; d < SCAN_D; ++d)
    rowbuf[d] = mb[(size_t)d * wpl + ln];

  int kept = 0;
  bool done = false;
  for (int r0 = 0; r0 < K && !done; r0 += SCAN_D) {
    #pragma unroll
    for (int d = 0; d < SCAN_D; ++d) {
      int r = r0 + d;
      int Wd = r >> 6;
      bool mybit = (lane == Wd) && ((alive >> (r & 63)) & 1ULL);
      unsigned long long b = __ballot(mybit);
      if (r < K && !done && b) {
        if (lane == 0) skept[kept] = (unsigned)r;
        kept++;
        if (kept >= MAX_OUT) done = true;
        alive &= ~rowbuf[d];   // clears self/earlier bits too: rows < r already decided
      }
      rowbuf[d] = mb[(size_t)(r + SCAN_D) * wpl + ln];  // padded rows: always in-bounds
    }
  }
  __syncthreads();
  const int base = img * M_TOT + LV_OFF[lvl];
  const size_t bo = (size_t)(img * 5 + lvl) * 1024;
  for (int i = lane; i < kept; i += 64) {
    unsigned r = skept[i];
    unsigned pp = n_pos[base + (int)r];
    kept_pos[bo + i] = pp;
    kept_key[bo + i] =
        ((unsigned long long)__float_as_uint(n_sc[base + (int)r]) << 32) |
        (unsigned)(~pp);
  }
  if (lane == 0) kept_cnt[img * 5 + lvl] = (unsigned)kept;
}

// ================= K3: per-image merge of kept lists -> output rows ===========
__global__ __launch_bounds__(1024) void k_merge(const float* cand_box,
    const float* cand_s, const unsigned* kept_pos,
    const unsigned long long* kept_key, const unsigned* kept_cnt, float* out) {
  const int img = blockIdx.x;
  const int tid = (int)threadIdx.x;
  __shared__ unsigned cnts[5];
  __shared__ unsigned long long skey[5][1024];
  if (tid < 5) {
    unsigned c = kept_cnt[img * 5 + tid];
    cnts[tid] = c < (unsigned)MAX_OUT ? c : (unsigned)MAX_OUT;
  }
  __syncthreads();
  for (int e = tid; e < 5 * 1024; e += 1024) {
    int l = e >> 10, s = e & 1023;
    skey[l][s] = (s < (int)cnts[l])
        ? kept_key[(size_t)(img * 5 + l) * 1024 + s] : 0ULL;
  }
  __syncthreads();
  unsigned T = cnts[0] + cnts[1] + cnts[2] + cnts[3] + cnts[4];
  unsigned Tc = T < (unsigned)MAX_OUT ? T : (unsigned)MAX_OUT;
  for (int r = (int)Tc + tid; r < MAX_OUT; r += 1024) {
    float* o = out + (size_t)img * (MAX_OUT * 5) + (size_t)r * 5;
    o[0] = 0.f; o[1] = 0.f; o[2] = 0.f; o[3] = 0.f; o[4] = 0.f;
  }
  for (int e = tid; e < 5 * 1024; e += 1024) {
    int l = e >> 10, s = e & 1023;
    if (s >= (int)cnts[l]) continue;
    unsigned long long k0 = skey[l][s];
    unsigned rank = (unsigned)s;
    #pragma unroll
    for (int l2 = 0; l2 < 5; ++l2) {
      if (l2 == l) continue;
      int lo = 0, hi = (int)cnts[l2];
      while (lo < hi) {
        int mid = (lo + hi) >> 1;
        if (skey[l2][mid] > k0) lo = mid + 1; else hi = mid;
      }
      rank += (unsigned)lo;
    }
    if (rank < (unsigned)MAX_OUT) {
      unsigned pos = kept_pos[(size_t)(img * 5 + l) * 1024 + s];
      const float* b = cand_box + (size_t)(img * M_TOT + pos) * 4;
      float* o = out + (size_t)img * (MAX_OUT * 5) + (size_t)rank * 5;
      o[0] = b[0]; o[1] = b[1]; o[2] = b[2]; o[3] = b[3];
      o[4] = cand_s[img * M_TOT + pos];
    }
  }
}

// ================= host launch =================
extern "C" void kernel_launch(void* const* d_in, const int* in_sizes, int n_in,
                              void* d_out, int out_size, void* d_ws, size_t ws_size,
                              hipStream_t stream) {
  Ptrs p;
  bool interleaved = (n_in == 10 && in_sizes[1] == 4 * 12 * 128 * 128);
  for (int l = 0; l < 5; ++l) {
    if (interleaved) {
      p.cls[l] = (const float*)d_in[2 * l];
      p.reg[l] = (const float*)d_in[2 * l + 1];
    } else {
      p.cls[l] = (const float*)d_in[l];
      p.reg[l] = (const float*)d_in[5 + l];
    }
  }
  uint8_t* w = (uint8_t*)d_ws;
  size_t o = 0;
  auto carve = [&](size_t bytes) {
    void* ptr = w + o;
    o += (bytes + 255) & ~(size_t)255;
    return ptr;
  };
  unsigned* u_arr = (unsigned*)carve((size_t)4 * U_PER_IMG * 4);
  float* cand_box = (float*)carve((size_t)4 * M_TOT * 4 * 4);
  float* cand_s = (float*)carve((size_t)4 * M_TOT * 4);
  float* n_x1 = (float*)carve((size_t)4 * M_TOT * 4);
  float* n_y1 = (float*)carve((size_t)4 * M_TOT * 4);
  float* n_x2 = (float*)carve((size_t)4 * M_TOT * 4);
  float* n_y2 = (float*)carve((size_t)4 * M_TOT * 4);
  float* n_ar = (float*)carve((size_t)4 * M_TOT * 4);
  float* n_sc = (float*)carve((size_t)4 * M_TOT * 4);
  unsigned* n_pos = (unsigned*)carve((size_t)4 * M_TOT * 4);
  unsigned* V_arr = (unsigned*)carve((size_t)20 * 4);
  unsigned* kept_pos = (unsigned*)carve((size_t)4 * 5 * 1024 * 4);
  unsigned long long* kept_key = (unsigned long long*)carve((size_t)4 * 5 * 1024 * 8);
  unsigned* kept_cnt = (unsigned*)carve((size_t)20 * 4);
  unsigned long long* mask = (unsigned long long*)carve((size_t)4 * MWORDS_PER_IMG * 8);
  (void)ws_size; (void)out_size;

  k_select<<<20, 1024, 0, stream>>>(p, u_arr, cand_box, cand_s,
      n_x1, n_y1, n_x2, n_y2, n_ar, n_sc, n_pos, V_arr);
  k_mask<<<dim3(807, 4), 256, 0, stream>>>(n_x1, n_y1, n_x2, n_y2, n_ar, mask);
  k_scan<<<20, 64, 0, stream>>>(mask, n_pos, n_sc, V_arr,
                                kept_pos, kept_key, kept_cnt);
  k_merge<<<4, 1024, 0, stream>>>(cand_box, cand_s, kept_pos, kept_key,
                                  kept_cnt, (float*)d_out);
}